// Round 9
// baseline (265.115 us; speedup 1.0000x reference)
//
#include <hip/hip_runtime.h>
#include <hip/hip_bf16.h>

typedef __attribute__((ext_vector_type(8))) short short8;
typedef __attribute__((ext_vector_type(4))) float f32x4;
typedef unsigned short u16;
typedef unsigned int   u32;

#define S_  2048
#define D_  1024
#define H_  16
#define DH_ 64
#define M_  4096     // B*S
#define K_  1024
#define N3_ 3072

// Q pre-scale: 1/sqrt(64) * log2(e)  (attn softmax runs in exp2 domain)
#define QSCL 0.18033688011112042f

// round-to-nearest-even fp32 -> bf16
__device__ __forceinline__ u16 f2bf(float f) {
    u32 u = __float_as_uint(f);
    u32 r = u + 0x7FFFu + ((u >> 16) & 1u);
    return (u16)(r >> 16);
}

__device__ __forceinline__ float fast_exp2(float x) {
#if __has_builtin(__builtin_amdgcn_exp2f)
    return __builtin_amdgcn_exp2f(x);
#else
    return __expf(x * 0.6931471805599453f);
#endif
}

// async global->LDS, 16B per lane (wave-uniform LDS base, per-lane global src)
__device__ __forceinline__ void gload_lds16(const void* g, void* l) {
    __builtin_amdgcn_global_load_lds(
        (const __attribute__((address_space(1))) u32*)g,
        (__attribute__((address_space(3))) u32*)l, 16, 0, 0);
}

// ---------------------------------------------------------------------------
// prep: fp32 -> bf16 straight convert (x)
// ---------------------------------------------------------------------------
__global__ __launch_bounds__(256) void convert_f32_bf16(
    const float* __restrict__ in, u16* __restrict__ out, int n4)
{
    int i = blockIdx.x * 256 + threadIdx.x;
    const int stride = gridDim.x * 256;
    for (; i < n4; i += stride) {
        float4 v = ((const float4*)in)[i];
        ushort4 o;
        o.x = f2bf(v.x); o.y = f2bf(v.y); o.z = f2bf(v.z); o.w = f2bf(v.w);
        ((ushort4*)out)[i] = o;
    }
}

// ---------------------------------------------------------------------------
// prep: transpose + convert.  in [rows][cols] f32  ->  out [cols][rows] bf16
// ---------------------------------------------------------------------------
__global__ __launch_bounds__(256) void transpose_f32_bf16(
    const float* __restrict__ in, u16* __restrict__ out, int rows, int cols)
{
    __shared__ float tile[32][33];
    const int tx = threadIdx.x & 31;
    const int ty = threadIdx.x >> 5;          // 0..7
    #pragma unroll
    for (int i = 0; i < 4; ++i) {
        int r = blockIdx.y * 32 + ty + i * 8;
        int c = blockIdx.x * 32 + tx;
        tile[ty + i * 8][tx] = in[(size_t)r * cols + c];
    }
    __syncthreads();
    #pragma unroll
    for (int i = 0; i < 4; ++i) {
        int orow = blockIdx.x * 32 + ty + i * 8;   // out row  (= in col)
        int ocol = blockIdx.y * 32 + tx;           // out col  (= in row)
        out[(size_t)orow * rows + ocol] = f2bf(tile[tx][ty + i * 8]);
    }
}

// ---------------------------------------------------------------------------
// bf16 MFMA GEMM, m97 structure: 128x128 tile, BK=32, 4 waves, 1D grid with
// XCD-aware swizzle (T1): blocks orig%8==x land on XCD x as one contiguous
// chunk of row-panels -> A-panel L2 locality.  nwg%8==0 guaranteed.
// EPI 0: QKV epilogue -> q (x QSCL) [bh][s][dh], k [bh][s][dh], v TRANSPOSED
//        [bh][dh][s] (packed uint2 stores).   EPI 1: proj, fp32 out + bias.
// ---------------------------------------------------------------------------
template <int EPI>
__global__ __launch_bounds__(256) void mfma_gemm(
    const u16* __restrict__ A, const u16* __restrict__ Bt,
    const float* __restrict__ bias,
    u16* __restrict__ qd, u16* __restrict__ kd, u16* __restrict__ vd,
    float* __restrict__ outp, int nx)
{
    __shared__ u16 As[128 * 32];   // [row][k] linear, 64B rows
    __shared__ u16 Bs[128 * 32];   // [outcol][k] linear

    const int t  = threadIdx.x;
    const int wv = t >> 6;                  // wave 0..3
    const int ln = t & 63;
    const int wr = wv >> 1, wc = wv & 1;    // 2x2 wave grid
    // T1 XCD swizzle (bijective: gridDim.x % 8 == 0)
    const int cpx  = gridDim.x >> 3;
    const int wgid = (blockIdx.x & 7) * cpx + (blockIdx.x >> 3);
    const int r0 = (wgid / nx) * 128;
    const int c0 = (wgid % nx) * 128;
    const int li = ln & 15, lq = ln >> 4;

    f32x4 acc[4][4];
    #pragma unroll
    for (int m = 0; m < 4; ++m)
        #pragma unroll
        for (int n = 0; n < 4; ++n) acc[m][n] = (f32x4){0.f, 0.f, 0.f, 0.f};

    for (int k0 = 0; k0 < K_; k0 += 32) {
        __syncthreads();
        #pragma unroll
        for (int qq = 0; qq < 2; ++qq) {
            const int slot = wv * 128 + qq * 64 + ln;      // 16B slots, 512 total
            const int row  = slot >> 2;
            const int col  = (slot & 3) * 8;
            gload_lds16(A  + (size_t)(r0 + row) * K_ + k0 + col,
                        &As[(size_t)(wv * 128 + qq * 64) * 8]);
            gload_lds16(Bt + (size_t)(c0 + row) * K_ + k0 + col,
                        &Bs[(size_t)(wv * 128 + qq * 64) * 8]);
        }
        __syncthreads();

        short8 af[4], bfr[4];
        const int qk = lq * 8;
        #pragma unroll
        for (int m = 0; m < 4; ++m)
            af[m] = *(const short8*)&As[(wr * 64 + m * 16 + li) * 32 + qk];
        #pragma unroll
        for (int n = 0; n < 4; ++n)
            bfr[n] = *(const short8*)&Bs[(wc * 64 + n * 16 + li) * 32 + qk];
        #pragma unroll
        for (int m = 0; m < 4; ++m)
            #pragma unroll
            for (int n = 0; n < 4; ++n)
                acc[m][n] = __builtin_amdgcn_mfma_f32_16x16x32_bf16(
                    af[m], bfr[n], acc[m][n], 0, 0, 0);
    }

    // C/D layout: col = lane&15, row = (lane>>4)*4 + reg
    if (EPI == 0) {
        #pragma unroll
        for (int n = 0; n < 4; ++n) {
            const int gcol  = c0 + wc * 64 + n * 16 + li;   // 0..3071
            const int which = gcol >> 10;                    // uniform per frag
            const int rem   = gcol & 1023;
            const int h     = rem >> 6;
            const int dh    = rem & 63;
            const float bb  = bias[gcol];
            if (which == 2) {
                // V transposed: [bh][dh][s], 4 consecutive s -> packed 8B store
                #pragma unroll
                for (int m = 0; m < 4; ++m) {
                    const int grow0 = r0 + wr * 64 + m * 16 + lq * 4;
                    const int b = grow0 >> 11, sb = grow0 & (S_ - 1);
                    uint2 pk;
                    pk.x = (u32)f2bf(acc[m][n][0] + bb) |
                           ((u32)f2bf(acc[m][n][1] + bb) << 16);
                    pk.y = (u32)f2bf(acc[m][n][2] + bb) |
                           ((u32)f2bf(acc[m][n][3] + bb) << 16);
                    *(uint2*)(vd + ((size_t)(b * H_ + h) * DH_ + dh) * S_ + sb) = pk;
                }
            } else {
                const float scl = (which == 0) ? QSCL : 1.0f;
                u16* dst = (which == 0) ? qd : kd;
                #pragma unroll
                for (int m = 0; m < 4; ++m)
                    #pragma unroll
                    for (int r = 0; r < 4; ++r) {
                        const int grow = r0 + wr * 64 + m * 16 + lq * 4 + r;
                        const int b = grow >> 11, s = grow & (S_ - 1);
                        dst[((size_t)(b * H_ + h) * S_ + s) * DH_ + dh] =
                            f2bf((acc[m][n][r] + bb) * scl);
                    }
            }
        }
    } else {
        #pragma unroll
        for (int n = 0; n < 4; ++n) {
            const int gcol = c0 + wc * 64 + n * 16 + li;
            const float bb = bias[gcol];
            #pragma unroll
            for (int m = 0; m < 4; ++m)
                #pragma unroll
                for (int r = 0; r < 4; ++r) {
                    const int grow = r0 + wr * 64 + m * 16 + lq * 4 + r;
                    outp[(size_t)grow * D_ + gcol] = acc[m][n][r] + bb;
                }
        }
    }
}

// ---------------------------------------------------------------------------
// flash attention v3.  4 waves, one (b,h) x 64-query tile per block.
// - double-buffered K/Vt LDS, ONE barrier per tile, async-stage split (T14):
//   next tile's global loads issued before compute, ds_write at top of next
//   iter (vmcnt wait hidden under a full tile of compute).
// - kv-identity frag remap: QK frag j <- K row li*4+j, so each lane's 4 P
//   values are kv-contiguous -> packed 8B P store (cvt_pk pair + b64).
// - exp2 domain (Q pre-scaled by log2e/8), defer-max THR=8 (T13).
// - XCD remap: 4 bh x 32 q-tiles per XCD -> K/V L2-resident per XCD.
// LDS 40KB -> 4 blocks/CU.
// ---------------------------------------------------------------------------
__global__ __launch_bounds__(256, 4) void attn_mfma(
    const u16* __restrict__ qws, const u16* __restrict__ kws,
    const u16* __restrict__ vtws, u16* __restrict__ ao)
{
    __shared__ u16 Ks[2][64 * 64];   // [kv][d]  swizzled, 128B rows
    __shared__ u16 Vt[2][64 * 64];   // [d][kv]  swizzled
    __shared__ u16 Ps[64 * 64];      // [qrow][kv] swizzled, wave-private strips

    const int t  = threadIdx.x;
    const int wv = t >> 6, ln = t & 63;
    const int li = ln & 15, lq = ln >> 4;

    // XCD-aware remap (assumes hw wgid%8 -> XCD; perf-only if wrong)
    const int f    = blockIdx.x;
    const int xcd  = f & 7;
    const int slot = f >> 3;              // 0..127
    const int bh   = xcd * 4 + (slot >> 5);
    const int q0   = (slot & 31) * 64;

    const u16* Kp  = kws  + (size_t)bh * S_ * DH_;
    const u16* Vtp = vtws + (size_t)bh * DH_ * S_;

    // Q fragments (read once): lane needs Q[q0+wv*16+li][ks*32+lq*8 ..]
    short8 aq[2];
    {
        const u16* Qp = qws + ((size_t)bh * S_ + q0 + wv * 16 + li) * DH_ + lq * 8;
        aq[0] = *(const short8*)(Qp);
        aq[1] = *(const short8*)(Qp + 32);
    }

    // staging slots: 512 chunks of 16B per 8KB tile, 2 per thread
    const int s0 = t, s1 = t + 256;
    const int row0 = s0 >> 3, c0e = (s0 & 7) * 8;
    const int row1 = s1 >> 3, c1e = (s1 & 7) * 8;
    const int off0 = (row0 * 128 + c0e * 2) ^ ((row0 & 7) << 4);
    const int off1 = (row1 * 128 + c1e * 2) ^ ((row1 & 7) << 4);

    // prologue: tile 0 in flight
    short8 ldK0 = *(const short8*)(Kp  + (size_t)row0 * DH_ + c0e);
    short8 ldK1 = *(const short8*)(Kp  + (size_t)row1 * DH_ + c1e);
    short8 ldV0 = *(const short8*)(Vtp + (size_t)row0 * S_  + c0e);
    short8 ldV1 = *(const short8*)(Vtp + (size_t)row1 * S_  + c1e);

    f32x4 o[4];
    #pragma unroll
    for (int n = 0; n < 4; ++n) o[n] = (f32x4){0.f, 0.f, 0.f, 0.f};
    float mrow[4] = {-3e38f, -3e38f, -3e38f, -3e38f};
    float lrow[4] = {0.f, 0.f, 0.f, 0.f};

    for (int kt = 0; kt < S_ / 64; ++kt) {
        u16* Kb = Ks[kt & 1];
        u16* Vb = Vt[kt & 1];
        // write staged tile (vmcnt wait here, hidden under previous compute)
        *(short8*)((char*)Kb + off0) = ldK0;
        *(short8*)((char*)Kb + off1) = ldK1;
        *(short8*)((char*)Vb + off0) = ldV0;
        *(short8*)((char*)Vb + off1) = ldV1;
        // issue next tile's loads (latency hides under this tile's compute)
        if (kt + 1 < S_ / 64) {
            const int k0n = (kt + 1) * 64;
            ldK0 = *(const short8*)(Kp  + (size_t)(k0n + row0) * DH_ + c0e);
            ldK1 = *(const short8*)(Kp  + (size_t)(k0n + row1) * DH_ + c1e);
            ldV0 = *(const short8*)(Vtp + (size_t)row0 * S_ + k0n + c0e);
            ldV1 = *(const short8*)(Vtp + (size_t)row1 * S_ + k0n + c1e);
        }
        __syncthreads();   // staged writes visible; also orders buf reuse (WAR)

        // S = Q K^T ; frag j holds kv rows li*4+j  (kv-identity remap)
        f32x4 sacc[4];
        #pragma unroll
        for (int j = 0; j < 4; ++j) sacc[j] = (f32x4){0.f, 0.f, 0.f, 0.f};
        __builtin_amdgcn_s_setprio(1);
        #pragma unroll
        for (int ks = 0; ks < 2; ++ks) {
            #pragma unroll
            for (int j = 0; j < 4; ++j) {
                const int rrow = li * 4 + j;
                const int roff = (rrow * 128 + ks * 64 + lq * 16) ^ ((rrow & 7) << 4);
                short8 bk = *(const short8*)((char*)Kb + roff);
                sacc[j] = __builtin_amdgcn_mfma_f32_16x16x32_bf16(aq[ks], bk, sacc[j], 0, 0, 0);
            }
        }
        __builtin_amdgcn_s_setprio(0);

        // row maxes (rows lq*4+r, reduce over 16 li lanes)
        float rmx[4];
        #pragma unroll
        for (int r = 0; r < 4; ++r) {
            float mx = fmaxf(fmaxf(sacc[0][r], sacc[1][r]), fmaxf(sacc[2][r], sacc[3][r]));
            mx = fmaxf(mx, __shfl_xor(mx, 1));
            mx = fmaxf(mx, __shfl_xor(mx, 2));
            mx = fmaxf(mx, __shfl_xor(mx, 4));
            mx = fmaxf(mx, __shfl_xor(mx, 8));
            rmx[r] = mx;
        }
        // defer-max: rescale only if some row grew past THR=8 (exact when skipped)
        const bool grow = (rmx[0] > mrow[0] + 8.f) | (rmx[1] > mrow[1] + 8.f) |
                          (rmx[2] > mrow[2] + 8.f) | (rmx[3] > mrow[3] + 8.f);
        if (__any(grow)) {
            #pragma unroll
            for (int r = 0; r < 4; ++r) {
                const float mnew = fmaxf(mrow[r], rmx[r]);
                const float scl  = fast_exp2(mrow[r] - mnew);
                lrow[r] *= scl;
                #pragma unroll
                for (int n = 0; n < 4; ++n) o[n][r] *= scl;
                mrow[r] = mnew;
            }
        }
        // P = 2^(S - m), packed store (lane's 4 values kv-contiguous)
        #pragma unroll
        for (int r = 0; r < 4; ++r) {
            const float p0 = fast_exp2(sacc[0][r] - mrow[r]);
            const float p1 = fast_exp2(sacc[1][r] - mrow[r]);
            const float p2 = fast_exp2(sacc[2][r] - mrow[r]);
            const float p3 = fast_exp2(sacc[3][r] - mrow[r]);
            float rs = p0 + p1 + p2 + p3;
            rs += __shfl_xor(rs, 1);
            rs += __shfl_xor(rs, 2);
            rs += __shfl_xor(rs, 4);
            rs += __shfl_xor(rs, 8);
            lrow[r] += rs;
            __hip_bfloat162 h01 = __float22bfloat162_rn(make_float2(p0, p1));
            __hip_bfloat162 h23 = __float22bfloat162_rn(make_float2(p2, p3));
            uint2 pk;
            pk.x = *(const u32*)&h01;
            pk.y = *(const u32*)&h23;
            const int prow = wv * 16 + lq * 4 + r;
            const int pb   = (prow * 128 + li * 8) ^ ((prow & 7) << 4);
            *(uint2*)((char*)Ps + pb) = pk;
        }

        // O += P V
        __builtin_amdgcn_s_setprio(1);
        #pragma unroll
        for (int ks = 0; ks < 2; ++ks) {
            const int arow = wv * 16 + li;
            const int aoff = (arow * 128 + ks * 64 + lq * 16) ^ ((li & 7) << 4);
            short8 ap = *(const short8*)((char*)Ps + aoff);
            #pragma unroll
            for (int n = 0; n < 4; ++n) {
                const int vrow = n * 16 + li;
                const int voff = (vrow * 128 + ks * 64 + lq * 16) ^ ((li & 7) << 4);
                short8 bv = *(const short8*)((char*)Vb + voff);
                o[n] = __builtin_amdgcn_mfma_f32_16x16x32_bf16(ap, bv, o[n], 0, 0, 0);
            }
        }
        __builtin_amdgcn_s_setprio(0);
    }

    // normalize + write merged-head bf16 [B*S][D]
    const int b = bh >> 4, h = bh & 15;
    #pragma unroll
    for (int r = 0; r < 4; ++r) {
        const float inv = 1.0f / lrow[r];
        const int s = q0 + wv * 16 + lq * 4 + r;
        #pragma unroll
        for (int n = 0; n < 4; ++n) {
            const int col = h * 64 + n * 16 + li;
            ao[((size_t)b * S_ + s) * D_ + col] = f2bf(o[n][r] * inv);
        }
    }
}

// ---------------------------------------------------------------------------
extern "C" void kernel_launch(void* const* d_in, const int* in_sizes, int n_in,
                              void* d_out, int out_size, void* d_ws, size_t ws_size,
                              hipStream_t stream)
{
    const float* x      = (const float*)d_in[0];
    const float* w_attn = (const float*)d_in[1];
    const float* b_attn = (const float*)d_in[2];
    const float* w_proj = (const float*)d_in[3];
    const float* b_proj = (const float*)d_in[4];
    float* out = (float*)d_out;

    char* ws = (char*)d_ws;
    u16* x_bf = (u16*)(ws);                              //  8 MB  [4096][1024]
    u16* wat  = (u16*)(ws + 8388608);                    //  6 MB  [3072][1024] (W_attn^T)
    u16* wpj  = (u16*)(ws + 14680064);                   //  2 MB  [1024][1024] (W_proj^T)
    u16* qws  = (u16*)(ws + 16777216);                   //  8 MB  [32][2048][64] (pre-scaled, log2e folded)
    u16* kws  = (u16*)(ws + 25165824);                   //  8 MB  [32][2048][64]
    u16* vtws = (u16*)(ws + 33554432);                   //  8 MB  [32][64][2048]  V^T
    u16* ao   = (u16*)(ws + 41943040);                   //  8 MB  [4096][1024]
    // total 48 MB

    convert_f32_bf16<<<1024, 256, 0, stream>>>(x, x_bf, M_ * K_ / 4);
    transpose_f32_bf16<<<dim3(N3_ / 32, K_ / 32), 256, 0, stream>>>(w_attn, wat, K_, N3_);
    transpose_f32_bf16<<<dim3(D_ / 32, K_ / 32), 256, 0, stream>>>(w_proj, wpj, K_, D_);

    // QKV: 24x32 = 768 tiles (768 % 8 == 0 -> bijective XCD swizzle)
    mfma_gemm<0><<<dim3((N3_ / 128) * (M_ / 128)), 256, 0, stream>>>(
        x_bf, wat, b_attn, qws, kws, vtws, nullptr, N3_ / 128);

    attn_mfma<<<dim3(1024), 256, 0, stream>>>(qws, kws, vtws, ao);

    // proj: 8x32 = 256 tiles
    mfma_gemm<1><<<dim3((D_ / 128) * (M_ / 128)), 256, 0, stream>>>(
        ao, wpj, b_proj, nullptr, nullptr, nullptr, out, D_ / 128);
}